// Round 2
// baseline (132.265 us; speedup 1.0000x reference)
//
#include <hip/hip_runtime.h>
#include <math.h>

#define B 2
#define S 48
#define D 256
#define H 8
#define DH 32
#define N (S*S)      // 2304
#define BN (B*N)     // 4608
#define BH (B*H)     // 16
#define KS 6         // split-K over keys
#define KPZ (N/KS)   // 384 = 3 tiles of 128
#define NE ((size_t)BN*D)
#define BHN (BH*N)

typedef _Float16 half8 __attribute__((ext_vector_type(8)));
typedef _Float16 half4_t __attribute__((ext_vector_type(4)));
typedef __fp16 fp16x2 __attribute__((ext_vector_type(2)));
typedef unsigned short ushort8_t __attribute__((ext_vector_type(8)));
typedef float floatx4 __attribute__((ext_vector_type(4)));

__device__ __forceinline__ half8 cvt8(const float* v) {
    half8 h;
    #pragma unroll
    for (int j = 0; j < 8; j++) h[j] = (_Float16)v[j];
    return h;
}

// ---------------------------------------------------------------------------
// One-time prep: (a) blocks 0..63 transpose+convert Wq/Wk/Wv/Wo (f32 [k][c])
// into fp16 Wt [z][c][k]; (b) blocks 64.. convert x to fp16 row-major.
// Removes the 72x/144x redundant per-block W gather+convert from proj/outproj.
// ---------------------------------------------------------------------------
__global__ __launch_bounds__(256) void prep_kernel(
    const float* __restrict__ x,
    const float* __restrict__ Wq, const float* __restrict__ Wk,
    const float* __restrict__ Wv, const float* __restrict__ Wo,
    _Float16* __restrict__ xh, _Float16* __restrict__ Wt)
{
    __shared__ __align__(16) _Float16 Ls[64 * 72];
    const int t = threadIdx.x;
    const int bid = blockIdx.x;
    if (bid < 64) {
        const int z = bid >> 4, tile = bid & 15;
        const int k0 = (tile >> 2) * 64, c0 = (tile & 3) * 64;
        const float* W = (z == 0) ? Wq : (z == 1) ? Wk : (z == 2) ? Wv : Wo;
        #pragma unroll
        for (int r = 0; r < 4; r++) {
            int k = r * 16 + (t >> 4);
            int c = (t & 15) * 4;
            float4 f = *(const float4*)(W + (size_t)(k0 + k) * D + c0 + c);
            Ls[(c + 0) * 72 + k] = (_Float16)f.x;
            Ls[(c + 1) * 72 + k] = (_Float16)f.y;
            Ls[(c + 2) * 72 + k] = (_Float16)f.z;
            Ls[(c + 3) * 72 + k] = (_Float16)f.w;
        }
        __syncthreads();
        #pragma unroll
        for (int i = 0; i < 2; i++) {
            int u = i * 256 + t;
            int c = u >> 3, ko = (u & 7) * 8;
            *(ushort8_t*)(Wt + (size_t)(z * D + c0 + c) * D + k0 + ko) =
                *(const ushort8_t*)(Ls + c * 72 + ko);
        }
    } else {
        size_t g = ((size_t)(bid - 64) * 256 + t) * 8;
        float4 f0 = *(const float4*)(x + g);
        float4 f1 = *(const float4*)(x + g + 4);
        float v[8] = {f0.x, f0.y, f0.z, f0.w, f1.x, f1.y, f1.z, f1.w};
        *(half8*)(xh + g) = cvt8(v);
    }
}

// ---------------------------------------------------------------------------
// QKV projection from pre-converted fp16 xh and Wt. 64x128 tiles; W^T staged
// to LDS via coalesced ushort8 (4 loads + 4 LDS writes/thread/kchunk instead
// of 32 f32 loads + 32 cvts). grid (72, 2, 3). Outputs: q,k (BH,N,DH) fp16
// (q pre-scaled log2e/sqrt(DH)); v TRANSPOSED (BH,DH,N) fp16.
// ---------------------------------------------------------------------------
__global__ __launch_bounds__(256) void proj_kernel(
    const _Float16* __restrict__ xh, const _Float16* __restrict__ Wt,
    const float* __restrict__ bq, const float* __restrict__ bk,
    const float* __restrict__ bv,
    _Float16* __restrict__ qbuf, _Float16* __restrict__ kbuf,
    _Float16* __restrict__ vtbuf)
{
    __shared__ __align__(16) _Float16 BhS[128 * 72];   // 18.4 KB

    const int z = blockIdx.z;
    const _Float16* Wz = Wt + (size_t)z * D * D;
    const float* bias = (z == 0) ? bq : (z == 1) ? bk : bv;
    const float scale = (z == 0) ? rsqrtf((float)DH) * 1.44269504f : 1.0f;

    const int t = threadIdx.x;
    const int wv2 = t >> 6, lane = t & 63, l15 = lane & 15, quad = lane >> 4;
    const int rowb = blockIdx.x * 64;
    const int colb = blockIdx.y * 128;
    const int grow = rowb + wv2 * 16 + l15;
    floatx4 acc[8] = {{0,0,0,0},{0,0,0,0},{0,0,0,0},{0,0,0,0},
                      {0,0,0,0},{0,0,0,0},{0,0,0,0},{0,0,0,0}};

    for (int kb0 = 0; kb0 < D; kb0 += 64) {
        __syncthreads();
        // B: 128 cols x 64 k fp16, coalesced 128B runs per col
        #pragma unroll
        for (int i = 0; i < 4; i++) {
            int u = i * 256 + t;
            int cc = u >> 3, k0 = (u & 7) * 8;
            *(ushort8_t*)(BhS + cc * 72 + k0) =
                *(const ushort8_t*)(Wz + (size_t)(colb + cc) * D + kb0 + k0);
        }
        __syncthreads();
        #pragma unroll
        for (int ksx = 0; ksx < 2; ksx++) {
            half8 ah = *(const half8*)(xh + (size_t)grow * D + kb0 + ksx * 32 + quad * 8);
            #pragma unroll
            for (int cg = 0; cg < 8; cg++) {
                half8 bh8 = *(const half8*)(BhS + (cg * 16 + l15) * 72 + ksx * 32 + quad * 8);
                acc[cg] = __builtin_amdgcn_mfma_f32_16x16x32_f16(ah, bh8, acc[cg], 0, 0, 0);
            }
        }
    }

    const int bb = (rowb >= N) ? 1 : 0;
    #pragma unroll
    for (int cg = 0; cg < 8; cg++) {
        int col = colb + cg * 16 + l15;
        int hh = col >> 5, dh = col & 31;
        float bs = bias[col];
        if (z < 2) {
            _Float16* op = (z == 0) ? qbuf : kbuf;
            #pragma unroll
            for (int r = 0; r < 4; r++) {
                int n = rowb + wv2 * 16 + quad * 4 + r - bb * N;
                float v = (acc[cg][r] + bs) * scale;
                op[((size_t)(bb * H + hh) * N + n) * DH + dh] = (_Float16)v;
            }
        } else {
            int n0 = rowb + wv2 * 16 + quad * 4 - bb * N;
            half4_t pk;
            #pragma unroll
            for (int r = 0; r < 4; r++) pk[r] = (_Float16)(acc[cg][r] + bs);
            *(half4_t*)(vtbuf + ((size_t)(bb * H + hh) * DH + dh) * N + n0) = pk;
        }
    }
}

// ---------------------------------------------------------------------------
// Flash attention (S^T register-P), 128-key LDS tiles. grid (18, BH, KS),
// 256 thr = 4 waves x 32 queries. QK^T 16x16x32 mfma; exp2 in place; packed
// rtz cvt for P; P^T C-frag feeds PV (A=V^T from LDS, K=16 mfma).
// Fixed-max softmax, fp16 split-K partials. lpart layout [row][h][kz] so the
// outproj merge reads it coalesced.
// ---------------------------------------------------------------------------
__global__ __launch_bounds__(256) void attn_kernel(
    const _Float16* __restrict__ qbuf, const _Float16* __restrict__ kbuf,
    const _Float16* __restrict__ vtbuf,
    _Float16* __restrict__ ctx_part, float* __restrict__ lpart)
{
    __shared__ __align__(16) _Float16 Ks[128 * 40];   // 10 KB
    __shared__ __align__(16) _Float16 Vt[32 * 136];   // 8.5 KB [d][key]

    const int t = threadIdx.x;
    const int wv2 = t >> 6, lane = t & 63, l15 = lane & 15, quad = lane >> 4;
    const int bh = blockIdx.y, kz = blockIdx.z;
    const int qbase = blockIdx.x * 128 + wv2 * 32;

    half8 bq8[2];
    #pragma unroll
    for (int qg = 0; qg < 2; qg++)
        bq8[qg] = *(const half8*)(qbuf +
            ((size_t)bh * N + qbase + qg * 16 + l15) * DH + quad * 8);

    floatx4 acc[2][2] = {{{0,0,0,0},{0,0,0,0}},{{0,0,0,0},{0,0,0,0}}};
    float lsum[2] = {0.f, 0.f};

    for (int it = 0; it < KPZ / 128; it++) {
        const int key0 = kz * KPZ + it * 128;
        __syncthreads();
        #pragma unroll
        for (int i = 0; i < 2; i++) {
            int u = i * 256 + t;
            // K: key = u>>2 (0..127), part = u&3
            *(ushort8_t*)(Ks + (u >> 2) * 40 + (u & 3) * 8) =
                *(const ushort8_t*)(kbuf + ((size_t)bh * N + key0 + (u >> 2)) * DH + (u & 3) * 8);
            // V: d = u>>4 (0..31), kp = u&15
            *(ushort8_t*)(Vt + (u >> 4) * 136 + (u & 15) * 8) =
                *(const ushort8_t*)(vtbuf + ((size_t)bh * DH + (u >> 4)) * N + key0 + (u & 15) * 8);
        }
        __syncthreads();

        #pragma unroll
        for (int kg = 0; kg < 8; kg++) {
            half8 ka = *(const half8*)(Ks + (kg * 16 + l15) * 40 + quad * 8);
            half4_t va0 = *(const half4_t*)(Vt + l15 * 136 + kg * 16 + quad * 4);
            half4_t va1 = *(const half4_t*)(Vt + (16 + l15) * 136 + kg * 16 + quad * 4);
            #pragma unroll
            for (int qg = 0; qg < 2; qg++) {
                floatx4 s = {0, 0, 0, 0};
                s = __builtin_amdgcn_mfma_f32_16x16x32_f16(ka, bq8[qg], s, 0, 0, 0);
                float p0 = exp2f(s[0]), p1 = exp2f(s[1]);
                float p2 = exp2f(s[2]), p3 = exp2f(s[3]);
                lsum[qg] += (p0 + p1) + (p2 + p3);
                union { fp16x2 h2[2]; half4_t h4; } pu;
                pu.h2[0] = __builtin_amdgcn_cvt_pkrtz(p0, p1);
                pu.h2[1] = __builtin_amdgcn_cvt_pkrtz(p2, p3);
                half4_t pf = pu.h4;
                acc[qg][0] = __builtin_amdgcn_mfma_f32_16x16x16f16(va0, pf, acc[qg][0], 0, 0, 0);
                acc[qg][1] = __builtin_amdgcn_mfma_f32_16x16x16f16(va1, pf, acc[qg][1], 0, 0, 0);
            }
        }
    }

    const int bb = bh >> 3, hh = bh & 7;
    #pragma unroll
    for (int qg = 0; qg < 2; qg++) {
        float ls = lsum[qg];
        ls += __shfl_xor(ls, 16);
        ls += __shfl_xor(ls, 32);
        int q = qbase + qg * 16 + l15;
        if (quad == 0)
            lpart[((size_t)(bb * N + q) * H + hh) * KS + kz] = ls;
        _Float16* crow = ctx_part + (size_t)kz * NE + ((size_t)bb * N + q) * D + hh * DH;
        half4_t c0, c1;
        #pragma unroll
        for (int r = 0; r < 4; r++) {
            c0[r] = (_Float16)acc[qg][0][r];
            c1[r] = (_Float16)acc[qg][1][r];
        }
        *(half4_t*)(crow + quad * 4)      = c0;
        *(half4_t*)(crow + 16 + quad * 4) = c1;
    }
}

// ---------------------------------------------------------------------------
// Output projection with fused merge. 16x128 tiles (576 blocks, 2.25
// waves/SIMD): A merged+normalized into LDS once per k-chunk; B-frags read
// directly from L2-resident fp16 Wo^T (no LDS, no per-block conversion).
// grid (288, 2). out fp32.
// ---------------------------------------------------------------------------
__global__ __launch_bounds__(256) void outproj_kernel(
    const _Float16* __restrict__ ctx_part, const float* __restrict__ lpart,
    const _Float16* __restrict__ Wot, const float* __restrict__ bo,
    float* __restrict__ out)
{
    __shared__ __align__(16) _Float16 AsS[16 * 72];    // 2.3 KB
    __shared__ float Linv[16 * 8];

    const int t = threadIdx.x;
    const int wv2 = t >> 6, lane = t & 63, l15 = lane & 15, quad = lane >> 4;
    const int rowb = blockIdx.x * 16;
    const int colb = blockIdx.y * 128;

    // per-block merged 1/l table: rows 0..15 x heads 0..7, coalesced reads
    if (t < 128) {
        int r = t >> 3, hh = t & 7;
        int row = rowb + r;
        const float* lp = lpart + ((size_t)row * H + hh) * KS;
        float ls = 0.f;
        #pragma unroll
        for (int zz = 0; zz < KS; zz++) ls += lp[zz];
        Linv[t] = 1.0f / ls;
    }

    floatx4 acc[2] = {{0,0,0,0},{0,0,0,0}};

    for (int kb0 = 0; kb0 < D; kb0 += 64) {
        __syncthreads();
        // A: merge KS fp16 partials, normalize, to LDS (16 rows x 64 k)
        {
            int r = t >> 4, k0 = (t & 15) * 4;
            int row = rowb + r;
            int kcol = kb0 + k0;
            float linv = Linv[r * 8 + (kcol >> 5)];
            float v[4] = {};
            #pragma unroll
            for (int zz = 0; zz < KS; zz++) {
                half4_t h = *(const half4_t*)(ctx_part + (size_t)zz * NE + (size_t)row * D + kcol);
                #pragma unroll
                for (int j = 0; j < 4; j++) v[j] += (float)h[j];
            }
            half4_t hv;
            #pragma unroll
            for (int j = 0; j < 4; j++) hv[j] = (_Float16)(v[j] * linv);
            *(half4_t*)(AsS + r * 72 + k0) = hv;
        }
        __syncthreads();
        #pragma unroll
        for (int ksx = 0; ksx < 2; ksx++) {
            half8 ah = *(const half8*)(AsS + l15 * 72 + ksx * 32 + quad * 8);
            #pragma unroll
            for (int cg = 0; cg < 2; cg++) {
                half8 bh8 = *(const half8*)(Wot +
                    (size_t)(colb + wv2 * 32 + cg * 16 + l15) * D + kb0 + ksx * 32 + quad * 8);
                acc[cg] = __builtin_amdgcn_mfma_f32_16x16x32_f16(ah, bh8, acc[cg], 0, 0, 0);
            }
        }
    }

    #pragma unroll
    for (int cg = 0; cg < 2; cg++) {
        int col = colb + wv2 * 32 + cg * 16 + l15;
        float bs = bo[col];
        #pragma unroll
        for (int r = 0; r < 4; r++) {
            int row = rowb + quad * 4 + r;
            out[(size_t)row * D + col] = acc[cg][r] + bs;
        }
    }
}

extern "C" void kernel_launch(void* const* d_in, const int* in_sizes, int n_in,
                              void* d_out, int out_size, void* d_ws, size_t ws_size,
                              hipStream_t stream)
{
    const float* x  = (const float*)d_in[0];
    const float* Wq = (const float*)d_in[1];
    const float* bq = (const float*)d_in[2];
    const float* Wk = (const float*)d_in[3];
    const float* bk = (const float*)d_in[4];
    const float* Wv = (const float*)d_in[5];
    const float* bv = (const float*)d_in[6];
    const float* Wo = (const float*)d_in[7];
    const float* bo = (const float*)d_in[8];
    float* out = (float*)d_out;

    _Float16* ctx_part = (_Float16*)d_ws;                   // KS*NE halfs
    float* lpart    = (float*)(ctx_part + (size_t)KS * NE); // KS*BHN fp32 ([row][h][kz])
    _Float16* qbuf  = (_Float16*)(lpart + (size_t)KS * BHN);
    _Float16* kbuf  = qbuf + NE;
    _Float16* vtbuf = kbuf + NE;
    _Float16* xh    = vtbuf + NE;                           // NE halfs
    _Float16* Wt    = xh + NE;                              // 4*D*D halfs

    prep_kernel<<<dim3(64 + (int)(NE / 2048)), 256, 0, stream>>>(
        x, Wq, Wk, Wv, Wo, xh, Wt);

    proj_kernel<<<dim3(BN / 64, D / 128, 3), 256, 0, stream>>>(
        xh, Wt, bq, bk, bv, qbuf, kbuf, vtbuf);

    attn_kernel<<<dim3(N / 128, BH, KS), 256, 0, stream>>>(
        qbuf, kbuf, vtbuf, ctx_part, lpart);

    outproj_kernel<<<dim3(BN / 16, D / 128), 256, 0, stream>>>(
        ctx_part, lpart, Wt + 3 * (size_t)D * D, bo, out);
}